// Round 2
// baseline (417.609 us; speedup 1.0000x reference)
//
#include <hip/hip_runtime.h>
#include <hip/hip_bf16.h>
#include <stdint.h>

#define BATCH 32
#define CIN   256
#define COUT  256
#define FH    64
#define FW    64
#define NK    4
#define CTX   256
#define TEMP  30.0f

typedef __attribute__((ext_vector_type(8))) short bf16x8;
typedef __attribute__((ext_vector_type(4))) float f32x4;

__device__ __forceinline__ unsigned short f2bf(float f) {
    union { float f; uint32_t u; } a; a.f = f;
    uint32_t r = a.u + 0x7fffu + ((a.u >> 16) & 1u);
    return (unsigned short)(r >> 16);
}

// ws layout
#define WMIX_OFF  1024
#define WMIX_BYTES (32u * 9u * 8u * 4u * 256u * 16u)        // 37,748,736
#define XP_OFF    (WMIX_OFF + WMIX_BYTES)
// xp: [b][ch8][q4][y66][col68][r8] bf16  -> 32*8*4*66*68*16 B = 73,383,936

// ---------------- Kernel 1: expert mix (attention fused) --------------------
// Attention: 8 (nb,k) pairs x 32-lane partial dot, shuffle-reduce, softmax in
// LDS. Then two-phase LDS transpose mix (unchanged from prev round).
__global__ __launch_bounds__(256, 2) void mix_kernel(
        const float* __restrict__ weight,
        const float* __restrict__ g,
        const float* __restrict__ dw,
        const float* __restrict__ db,
        uint32_t* __restrict__ wmix) {
    __shared__ __align__(16) short S[2 * 8 * 2308];   // 73,856 B
    __shared__ float logit_s[8];
    __shared__ float att_s[8];

    const int t   = threadIdx.x;
    const int cog = blockIdx.x;          // 0..31, 8 co each
    const int bg  = blockIdx.y;          // 0..15, 2 b each
    const int co0 = cog * 8;
    const int b0  = bg * 2;
    const size_t EST = (size_t)COUT * CIN * 9;       // floats per expert

    // ---- fused attention for b0, b0+1 ----
    {
        const int p  = t >> 5;           // pair: nb = p>>2, k = p&3
        const int i0 = t & 31;
        const int nb = p >> 2, k = p & 3;
        const float* gp = g + (size_t)(b0 + nb) * CTX;
        float part = 0.f;
#pragma unroll
        for (int j = 0; j < 8; ++j) {
            const int i = i0 + j * 32;
            part += gp[i] * dw[i * NK + k];
        }
#pragma unroll
        for (int m = 1; m <= 16; m <<= 1) part += __shfl_xor(part, m);
        if (i0 == 0) logit_s[p] = part + db[k];
    }
    __syncthreads();
    if (t < 8) {
        const int nb = t >> 2;
        const float l0 = logit_s[nb * 4 + 0] * (1.f / TEMP);
        const float l1 = logit_s[nb * 4 + 1] * (1.f / TEMP);
        const float l2 = logit_s[nb * 4 + 2] * (1.f / TEMP);
        const float l3 = logit_s[nb * 4 + 3] * (1.f / TEMP);
        const float m  = fmaxf(fmaxf(l0, l1), fmaxf(l2, l3));
        const float e0 = expf(l0 - m), e1 = expf(l1 - m);
        const float e2 = expf(l2 - m), e3 = expf(l3 - m);
        const float s  = e0 + e1 + e2 + e3;
        const int   k  = t & 3;
        const float e  = (k == 0) ? e0 : (k == 1) ? e1 : (k == 2) ? e2 : e3;
        att_s[t] = e / s;
    }
    __syncthreads();

    float a[2][4];
#pragma unroll
    for (int nb = 0; nb < 2; ++nb)
#pragma unroll
        for (int k = 0; k < 4; ++k)
            a[nb][k] = att_s[nb * 4 + k];

    // ---- phase 1: weight -> mixed bf16 in LDS ----
    const int co_l  = t >> 5;            // 0..7
    const int inner = t & 31;            // 0..31
    const float* wbase = weight + (size_t)(co0 + co_l) * 2304;

#pragma unroll 2
    for (int i = 0; i < 18; ++i) {
        const int e4 = inner + 32 * i;   // float4 index within (k,co), 0..575
        float4 w[4];
#pragma unroll
        for (int k = 0; k < 4; ++k)
            w[k] = *(const float4*)(wbase + k * EST + (size_t)e4 * 4);
#pragma unroll
        for (int nb = 0; nb < 2; ++nb) {
            float mx = a[nb][0] * w[0].x + a[nb][1] * w[1].x + a[nb][2] * w[2].x + a[nb][3] * w[3].x;
            float my = a[nb][0] * w[0].y + a[nb][1] * w[1].y + a[nb][2] * w[2].y + a[nb][3] * w[3].y;
            float mz = a[nb][0] * w[0].z + a[nb][1] * w[1].z + a[nb][2] * w[2].z + a[nb][3] * w[3].z;
            float mw = a[nb][0] * w[0].w + a[nb][1] * w[1].w + a[nb][2] * w[2].w + a[nb][3] * w[3].w;
            uint32_t lo = (uint32_t)f2bf(mx) | ((uint32_t)f2bf(my) << 16);
            uint32_t hi = (uint32_t)f2bf(mz) | ((uint32_t)f2bf(mw) << 16);
            uint2* d = (uint2*)(S + ((nb * 8 + co_l) * 2308 + e4 * 4));
            *d = make_uint2(lo, hi);
        }
    }
    __syncthreads();

    // ---- phase 2: LDS -> wmix, coalesced 16B stores ----
    const int co_w = t & 7;              // 0..7
    const int slot = t >> 3;             // 0..31
#pragma unroll 2
    for (int j = 0; j < 18; ++j) {
        const int GG  = j * 32 + slot;   // 0..575 over (b_l, tap, ch, q)
        const int b_l = (GG >= 288) ? 1 : 0;
        const int rem = GG - b_l * 288;  // tap*32 + ch*4 + q
        const int tap = rem >> 5;
        const int ch  = (rem >> 2) & 7;
        const int q   = rem & 3;
        const short* sp = S + (b_l * 8 + co_w) * 2308;
        const int ebase = (ch * 32 + q * 8) * 9 + tap;
        uint32_t d[4];
#pragma unroll
        for (int rp = 0; rp < 4; ++rp) {
            uint32_t lo = (uint16_t)sp[ebase + (2 * rp) * 9];
            uint32_t hi = (uint16_t)sp[ebase + (2 * rp + 1) * 9];
            d[rp] = lo | (hi << 16);
        }
        uint32_t* dst = wmix +
            ((((size_t)((b0 + b_l) * 9 + tap) * 8 + ch) * 4 + q) * 256 + co0 + co_w) * 4;
        *(uint4*)dst = make_uint4(d[0], d[1], d[2], d[3]);
    }
}

// ---------------- Kernel 2: x -> bf16 halo-padded xp ------------------------
// 6 y-rows per block (grid 11x8x32 = 2816 blocks); loads for the 6 rows are
// independent and pipeline, two barriers total per block.
__global__ __launch_bounds__(256) void xpad_kernel(const float* __restrict__ x,
                                                   uint32_t* __restrict__ xp) {
    __shared__ uint32_t P[6 * 1088];    // 26,112 B
    const int t  = threadIdx.x;
    const int yg = blockIdx.x;      // 0..10, rows yg*6 .. yg*6+5
    const int ch = blockIdx.y;      // 0..7
    const int b  = blockIdx.z;      // 0..31

    for (int i = t; i < 6 * 1088; i += 256) P[i] = 0;
    __syncthreads();

    const int ci_l = t >> 3;            // 0..31
    const int col0 = (t & 7) * 8;       // 0..56
    const int q = ci_l >> 3, r = ci_l & 7;
    unsigned short* Ps = (unsigned short*)P;

#pragma unroll
    for (int yy = 0; yy < 6; ++yy) {
        const int y = yg * 6 + yy;
        if (y >= 1 && y <= 64) {
            const float* xr = x + (((size_t)(b * 256 + ch * 32 + ci_l) * 64) + (y - 1)) * 64 + col0;
            float4 v0 = *(const float4*)xr;
            float4 v1 = *(const float4*)(xr + 4);
            unsigned short bf[8];
            bf[0] = f2bf(v0.x); bf[1] = f2bf(v0.y); bf[2] = f2bf(v0.z); bf[3] = f2bf(v0.w);
            bf[4] = f2bf(v1.x); bf[5] = f2bf(v1.y); bf[6] = f2bf(v1.z); bf[7] = f2bf(v1.w);
#pragma unroll
            for (int j = 0; j < 8; ++j)
                Ps[yy * 2176 + (q * 68 + (col0 + j + 1)) * 8 + r] = bf[j];
        }
    }
    __syncthreads();

    const int qo = t >> 6, l = t & 63;
#pragma unroll
    for (int yy = 0; yy < 6; ++yy) {
        const int y = yg * 6 + yy;
        uint32_t* base = xp + (((((size_t)(b * 8 + ch) * 4 + qo) * 66) + y) * 68) * 4;
#pragma unroll
        for (int i = 0; i < 4; ++i)
            base[l + i * 64] = P[yy * 1088 + qo * 272 + l + i * 64];
        if (l < 16) base[l + 256] = P[yy * 1088 + qo * 272 + l + 256];
    }
}

// ---------------- Kernel 3: implicit-GEMM conv, 2-phase pipelined -----------
// Block 256 thr (4 waves, 2co x 2px). Tile 128co x 128px (rows y0,y0+1).
// Double-buffered LDS; per phase: issue next-phase global_load_lds, then
// ds_read+MFMA current, one __syncthreads (vmcnt0+lgkmcnt0 drain) per phase.
// q-stride padded +16B to break the l4-group bank alias. XCD-swizzled grid.
__global__ __launch_bounds__(256, 2) void conv_mfma(
        const char* __restrict__ xp,
        const char* __restrict__ wmix,
        float* __restrict__ out) {
    // As: [dx3][q4][co128][r8], q-stride 2064 B (2048 + 16 pad), dx-stride 8256
    // Bs: [q4][row2][col68][r8], q-stride 2192 B (2176 + 16 pad)
    __shared__ __align__(16) char As[2][3 * 4 * 2064];   // 24,768 B each
    __shared__ __align__(16) char Bs[2][4 * 2192];       //  8,768 B each

    const int tid  = threadIdx.x;
    const int lane = tid & 63;
    const int wv   = tid >> 6;
    const int wm   = wv & 1;          // co half
    const int wn   = wv >> 1;         // px half == image row offset
    const int l4   = lane >> 4;       // k-quad
    const int m16  = lane & 15;

    // bijective XCD swizzle: 2048 blocks = 8 * 256
    const int bx  = blockIdx.x;
    const int wid = (bx & 7) * 256 + (bx >> 3);
    const int ptile = wid & 31;       // 0..31
    const int coT   = (wid >> 5) & 1; // 0..1
    const int b     = wid >> 6;       // 0..31
    const int y0    = ptile * 2;

    const char* wmix_b = wmix + (size_t)b * 9 * 8 * 4 * 256 * 16;
    const char* xp_b   = xp + (size_t)b * 8 * 4 * 66 * 68 * 16;

    f32x4 acc[4][4];
#pragma unroll
    for (int i = 0; i < 4; ++i)
#pragma unroll
        for (int j = 0; j < 4; ++j)
            acc[i][j] = (f32x4){0.f, 0.f, 0.f, 0.f};

    const int aLane = l4 * 2064 + wm * 1024 + m16 * 16;   // byte off in As buf
    const int bLane = l4 * 2192 + wn * 1088 + m16 * 16;   // byte off in Bs buf

    auto stage = [&](char* Asb, char* Bsb, int p) {
        const int ch = p / 3, dy = p - ch * 3;
        // ---- A staging: 24 segments of 1KB (6 per wave) ----
#pragma unroll
        for (int i = 0; i < 6; ++i) {
            const int s  = wv + i * 4;      // 0..23
            const int dx = s >> 3;
            const int q  = (s >> 1) & 3;
            const int h  = s & 1;
            const char* gsrc = wmix_b
                + ((size_t)((dy * 3 + dx) * 8 + ch) * 4 + q) * 4096
                + (coT * 128 + h * 64 + lane) * 16;
            char* ldst = Asb + dx * 8256 + q * 2064 + (h * 64 + lane) * 16;
            __builtin_amdgcn_global_load_lds(
                (const __attribute__((address_space(1))) void*)gsrc,
                (__attribute__((address_space(3))) void*)ldst, 16, 0, 0);
        }
        // ---- B staging: wave wv stages q=wv, rows yb..yb+1 (2176 B) ----
        const int yb = y0 + dy;     // padded-row index, 0..64
        const char* gsrc = xp_b
            + (((size_t)ch * 4 + wv) * 66 + yb) * 1088 + lane * 16;
        char* ldst = Bsb + wv * 2192 + lane * 16;
        __builtin_amdgcn_global_load_lds(
            (const __attribute__((address_space(1))) void*)gsrc,
            (__attribute__((address_space(3))) void*)ldst, 16, 0, 0);
        __builtin_amdgcn_global_load_lds(
            (const __attribute__((address_space(1))) void*)(gsrc + 1024),
            (__attribute__((address_space(3))) void*)(ldst + 1024), 16, 0, 0);
        if (lane < 8)
            __builtin_amdgcn_global_load_lds(
                (const __attribute__((address_space(1))) void*)(gsrc + 2048),
                (__attribute__((address_space(3))) void*)(ldst + 2048), 16, 0, 0);
    };

    stage(As[0], Bs[0], 0);
    __syncthreads();   // prologue staging visible (vmcnt0 drain inside)

#pragma unroll 1
    for (int p = 0; p < 24; ++p) {
        const int cur = p & 1;
        if (p < 23) stage(As[cur ^ 1], Bs[cur ^ 1], p + 1);

        const char* Asc = As[cur];
        const char* Bsc = Bs[cur];
#pragma unroll
        for (int dx = 0; dx < 3; ++dx) {
            bf16x8 a[4], bb[4];
#pragma unroll
            for (int sm = 0; sm < 4; ++sm)
                a[sm] = *(const bf16x8*)(Asc + dx * 8256 + aLane + sm * 256);
#pragma unroll
            for (int sn = 0; sn < 4; ++sn)
                bb[sn] = *(const bf16x8*)(Bsc + bLane + dx * 16 + sn * 256);
            __builtin_amdgcn_s_setprio(1);
#pragma unroll
            for (int sm = 0; sm < 4; ++sm)
#pragma unroll
                for (int sn = 0; sn < 4; ++sn)
                    acc[sm][sn] = __builtin_amdgcn_mfma_f32_16x16x32_bf16(
                        a[sm], bb[sn], acc[sm][sn], 0, 0, 0);
            __builtin_amdgcn_s_setprio(0);
        }
        __syncthreads();   // drains vmcnt (next staging) + lgkmcnt (our reads)
    }

    // ---- epilogue: D col=lane&15 (px), row=(lane>>4)*4+reg (co) ----
    const int y = y0 + wn;
#pragma unroll
    for (int sm = 0; sm < 4; ++sm) {
#pragma unroll
        for (int sn = 0; sn < 4; ++sn) {
#pragma unroll
            for (int r = 0; r < 4; ++r) {
                const int co = coT * 128 + wm * 64 + sm * 16 + l4 * 4 + r;
                const int xx = sn * 16 + m16;
                out[(((size_t)b * COUT + co) * FH + y) * FW + xx] = acc[sm][sn][r];
            }
        }
    }
}

extern "C" void kernel_launch(void* const* d_in, const int* in_sizes, int n_in,
                              void* d_out, int out_size, void* d_ws, size_t ws_size,
                              hipStream_t stream) {
    const float* x       = (const float*)d_in[0];
    const float* g       = (const float*)d_in[1];
    const float* weight  = (const float*)d_in[2];
    const float* dense_w = (const float*)d_in[3];
    const float* dense_b = (const float*)d_in[4];
    float* out = (float*)d_out;

    uint32_t* wmix = (uint32_t*)((char*)d_ws + WMIX_OFF);
    uint32_t* xp   = (uint32_t*)((char*)d_ws + XP_OFF);

    mix_kernel<<<dim3(32, 16), 256, 0, stream>>>(weight, g, dense_w, dense_b, wmix);
    xpad_kernel<<<dim3(11, 8, BATCH), 256, 0, stream>>>(x, xp);
    conv_mfma<<<2048, 256, 0, stream>>>((const char*)xp, (const char*)wmix, out);
}